// Round 3
// baseline (648.959 us; speedup 1.0000x reference)
//
#include <hip/hip_runtime.h>

typedef short short8  __attribute__((ext_vector_type(8)));
typedef short short4v __attribute__((ext_vector_type(4)));
typedef float float4v __attribute__((ext_vector_type(4)));
typedef int   int4v   __attribute__((ext_vector_type(4)));

__device__ __forceinline__ short f2bf(float f) {
    unsigned u = __builtin_bit_cast(unsigned, f);
    u += 0x7fff + ((u >> 16) & 1);   // RNE
    return (short)(u >> 16);
}

// ---------------------------------------------------------------------------
// Transpose 4 weight matrices [1024,1024] f32 -> bf16: Wt[n][k] = bf16(W[k][n])
// ---------------------------------------------------------------------------
__global__ __launch_bounds__(256) void transpose4(
    const float* __restrict__ W0, const float* __restrict__ W1,
    const float* __restrict__ W2, const float* __restrict__ W3,
    short* __restrict__ T0, short* __restrict__ T1,
    short* __restrict__ T2, short* __restrict__ T3)
{
    __shared__ short Tl[64 * 72];
    const int tid = threadIdx.x;
    const int mat = blockIdx.x >> 8;
    const int t   = blockIdx.x & 255;
    const int k0 = (t >> 4) * 64, n0 = (t & 15) * 64;
    const float* W = mat == 0 ? W0 : mat == 1 ? W1 : mat == 2 ? W2 : W3;
    short*       T = mat == 0 ? T0 : mat == 1 ? T1 : mat == 2 ? T2 : T3;
    #pragma unroll
    for (int i = 0; i < 4; i++) {
        int c = tid + i * 256;
        int row = c >> 4, c4 = (c & 15) * 4;
        float4v v = *(const float4v*)&W[(size_t)(k0 + row) * 1024 + n0 + c4];
        short4v s = {f2bf(v[0]), f2bf(v[1]), f2bf(v[2]), f2bf(v[3])};
        *(short4v*)&Tl[row * 72 + c4] = s;
    }
    __syncthreads();
    #pragma unroll
    for (int i = 0; i < 2; i++) {
        int c = tid + i * 256;
        int nrow = c >> 3, k8 = (c & 7) * 8;
        short8 v;
        #pragma unroll
        for (int e = 0; e < 8; e++) v[e] = Tl[(k8 + e) * 72 + nrow];
        *(short8*)&T[(size_t)(n0 + nrow) * 1024 + k0 + k8] = v;
    }
}

// ---------------------------------------------------------------------------
// C[M,N] = bf16(A[M,K]) @ Bt[N,K]^T + bias[N]
// A f32 (A_BF16=false) or bf16 (A_BF16=true); Bt bf16; bias f32;
// C bf16 (C_F32=false) or f32 (C_F32=true).
// 128x128 tile, 256 threads (4 waves 2x2, each wave 64x64), BK=32.
// ---------------------------------------------------------------------------
template<bool A_BF16, bool C_F32>
__global__ __launch_bounds__(256) void gemm_bt(
    const void* __restrict__ Av, const short* __restrict__ Bt,
    const float* __restrict__ bias, void* __restrict__ Cv,
    int M, int N, int K)
{
    __shared__ short As[128 * 40];
    __shared__ short Bs[128 * 40];
    const int tid = threadIdx.x;
    const int m0 = blockIdx.x * 128, n0 = blockIdx.y * 128;
    const int w = tid >> 6, lid = tid & 63, quad = lid >> 4, l15 = lid & 15;
    const int wrow = (w >> 1) * 64, wcol = (w & 1) * 64;

    float4v acc[4][4];
    #pragma unroll
    for (int i = 0; i < 4; i++)
        #pragma unroll
        for (int j = 0; j < 4; j++) acc[i][j] = (float4v){0.f, 0.f, 0.f, 0.f};

    for (int kb = 0; kb < K; kb += 32) {
        if constexpr (A_BF16) {
            const short* A = (const short*)Av;
            #pragma unroll
            for (int half = 0; half < 2; half++) {
                int row = (tid >> 2) + half * 64, sk8 = (tid & 3) * 8;
                *(short8*)&As[row * 40 + sk8] =
                    *(const short8*)&A[(size_t)(m0 + row) * K + kb + sk8];
            }
        } else {
            const float* A = (const float*)Av;
            #pragma unroll
            for (int i = 0; i < 4; i++) {
                int c = tid + i * 256;
                int row = c >> 3, c4 = (c & 7) * 4;
                float4v v = *(const float4v*)&A[(size_t)(m0 + row) * K + kb + c4];
                short4v s = {f2bf(v[0]), f2bf(v[1]), f2bf(v[2]), f2bf(v[3])};
                *(short4v*)&As[row * 40 + c4] = s;
            }
        }
        #pragma unroll
        for (int half = 0; half < 2; half++) {
            int row = (tid >> 2) + half * 64, sk8 = (tid & 3) * 8;
            *(short8*)&Bs[row * 40 + sk8] =
                *(const short8*)&Bt[(size_t)(n0 + row) * K + kb + sk8];
        }
        __syncthreads();
        short8 ar[4], br[4];
        #pragma unroll
        for (int i = 0; i < 4; i++)
            ar[i] = *(short8*)&As[(wrow + i * 16 + l15) * 40 + quad * 8];
        #pragma unroll
        for (int j = 0; j < 4; j++)
            br[j] = *(short8*)&Bs[(wcol + j * 16 + l15) * 40 + quad * 8];
        #pragma unroll
        for (int i = 0; i < 4; i++)
            #pragma unroll
            for (int j = 0; j < 4; j++)
                acc[i][j] = __builtin_amdgcn_mfma_f32_16x16x32_bf16(
                    ar[i], br[j], acc[i][j], 0, 0, 0);
        __syncthreads();
    }

    #pragma unroll
    for (int j = 0; j < 4; j++) {
        int n = n0 + wcol + j * 16 + l15;
        float bj = bias[n];
        #pragma unroll
        for (int i = 0; i < 4; i++) {
            #pragma unroll
            for (int r = 0; r < 4; r++) {
                int m = m0 + wrow + i * 16 + quad * 4 + r;
                if constexpr (C_F32)
                    ((float*)Cv)[(size_t)m * N + n] = acc[i][j][r] + bj;
                else
                    ((short*)Cv)[(size_t)m * N + n] = f2bf(acc[i][j][r] + bj);
            }
        }
    }
}

// ---------------------------------------------------------------------------
// Fused attention: per block = one (b,h) and 16 query rows.
// S = Q Kh^T / 8, mask, softmax -> P (f32 to attention output; bf16 to LDS),
// X = P @ Vh  -> X[b*S+s][h*64+d]   (bf16), softmax in f32
// ---------------------------------------------------------------------------
__global__ __launch_bounds__(256) void attn_kernel(
    const short* __restrict__ Q, const short* __restrict__ Kp,
    const short* __restrict__ V, const int* __restrict__ mask,
    float* __restrict__ attnOut, short* __restrict__ X)
{
    __shared__ short Pl[16 * 1032];     // bf16 P tile, pitch 1032
    __shared__ short Ql[16 * 72];       // Q tile
    __shared__ short KVl[256 * 72];     // K tile [256][72] / Vt tile [64][264]
    __shared__ int   maskl[1024];
    __shared__ float redmx[4][16];
    __shared__ float redsm[4][16];

    const int tid = threadIdx.x;
    const int w = tid >> 6, lid = tid & 63, quad = lid >> 4, l15 = lid & 15;
    const int bid = blockIdx.x;
    const int qb = bid & 63;            // 64 q-blocks of 16 rows
    const int bh = bid >> 6;            // b*16 + h
    const int b = bh >> 4, h = bh & 15;
    const int q0 = qb * 16;
    const size_t rowbase = (size_t)b * 1024 * 1024;

    *(int4v*)&maskl[tid * 4] = *(const int4v*)&mask[b * 1024 + tid * 4];
    {
        int row = tid >> 4, e4 = (tid & 15) * 4;
        *(short4v*)&Ql[row * 72 + e4] =
            *(const short4v*)&Q[rowbase + (size_t)(q0 + row) * 1024 + h * 64 + e4];
    }
    __syncthreads();

    short8 aq0 = *(short8*)&Ql[l15 * 72 + quad * 8];
    short8 aq1 = *(short8*)&Ql[l15 * 72 + 32 + quad * 8];

    // ---- S = Q K^T ----
    float4v accS[16];
    #pragma unroll
    for (int a = 0; a < 16; a++) accS[a] = (float4v){0.f, 0.f, 0.f, 0.f};

    for (int nk = 0; nk < 4; nk++) {
        #pragma unroll
        for (int i = 0; i < 8; i++) {
            int c = tid + i * 256;
            int row = c >> 3, k8 = (c & 7) * 8;
            *(short8*)&KVl[row * 72 + k8] = *(const short8*)
                &Kp[rowbase + (size_t)(nk * 256 + row) * 1024 + h * 64 + k8];
        }
        __syncthreads();
        #pragma unroll
        for (int jj = 0; jj < 4; jj++) {
            int nloc = (w * 4 + jj) * 16 + l15;
            short8 b0 = *(short8*)&KVl[nloc * 72 + quad * 8];
            short8 b1 = *(short8*)&KVl[nloc * 72 + 32 + quad * 8];
            int a = nk * 4 + jj;
            accS[a] = __builtin_amdgcn_mfma_f32_16x16x32_bf16(aq0, b0, accS[a], 0, 0, 0);
            accS[a] = __builtin_amdgcn_mfma_f32_16x16x32_bf16(aq1, b1, accS[a], 0, 0, 0);
        }
        __syncthreads();
    }

    // ---- scale + mask + softmax (f32) ----
    float mx[4] = {-3e38f, -3e38f, -3e38f, -3e38f};
    #pragma unroll
    for (int a = 0; a < 16; a++) {
        int col = (a >> 2) * 256 + (w * 4 + (a & 3)) * 16 + l15;
        bool keep = maskl[col] != 0;
        #pragma unroll
        for (int r = 0; r < 4; r++) {
            float s = accS[a][r] * 0.125f;
            s = keep ? s : -1e10f;
            accS[a][r] = s;
            mx[r] = fmaxf(mx[r], s);
        }
    }
    #pragma unroll
    for (int off = 1; off < 16; off <<= 1)
        #pragma unroll
        for (int r = 0; r < 4; r++) mx[r] = fmaxf(mx[r], __shfl_xor(mx[r], off));
    if (l15 == 0) {
        #pragma unroll
        for (int r = 0; r < 4; r++) redmx[w][quad * 4 + r] = mx[r];
    }
    __syncthreads();
    float mrow[4], sm[4] = {0.f, 0.f, 0.f, 0.f};
    #pragma unroll
    for (int r = 0; r < 4; r++) {
        int qr = quad * 4 + r;
        mrow[r] = fmaxf(fmaxf(redmx[0][qr], redmx[1][qr]),
                        fmaxf(redmx[2][qr], redmx[3][qr]));
    }
    #pragma unroll
    for (int a = 0; a < 16; a++)
        #pragma unroll
        for (int r = 0; r < 4; r++) {
            float e = __expf(accS[a][r] - mrow[r]);
            accS[a][r] = e;
            sm[r] += e;
        }
    #pragma unroll
    for (int off = 1; off < 16; off <<= 1)
        #pragma unroll
        for (int r = 0; r < 4; r++) sm[r] += __shfl_xor(sm[r], off);
    if (l15 == 0) {
        #pragma unroll
        for (int r = 0; r < 4; r++) redsm[w][quad * 4 + r] = sm[r];
    }
    __syncthreads();
    float inv[4];
    #pragma unroll
    for (int r = 0; r < 4; r++) {
        int qr = quad * 4 + r;
        inv[r] = 1.0f / (redsm[0][qr] + redsm[1][qr] + redsm[2][qr] + redsm[3][qr]);
    }

    // ---- P: f32 to attention output (64B segments/quad), bf16 to LDS ----
    const size_t abase = ((size_t)bh * 1024 + q0) * 1024;
    #pragma unroll
    for (int a = 0; a < 16; a++) {
        int col = (a >> 2) * 256 + (w * 4 + (a & 3)) * 16 + l15;
        #pragma unroll
        for (int r = 0; r < 4; r++) {
            float p = accS[a][r] * inv[r];
            attnOut[abase + (size_t)(quad * 4 + r) * 1024 + col] = p;
            Pl[(quad * 4 + r) * 1032 + col] = f2bf(p);
        }
    }
    __syncthreads();

    // ---- X = P @ V ----
    float4v accX = (float4v){0.f, 0.f, 0.f, 0.f};
    for (int kt = 0; kt < 4; kt++) {
        __syncthreads();   // prior KVl readers done before restage
        #pragma unroll
        for (int i = 0; i < 8; i++) {
            int c = tid + i * 256;
            int row = c >> 3, e8 = (c & 7) * 8;
            short8 v = *(const short8*)
                &V[rowbase + (size_t)(kt * 256 + row) * 1024 + h * 64 + e8];
            #pragma unroll
            for (int e = 0; e < 8; e++) KVl[(e8 + e) * 264 + row] = v[e];
        }
        __syncthreads();
        #pragma unroll
        for (int kk = 0; kk < 8; kk++) {
            short8 ap = *(short8*)&Pl[l15 * 1032 + kt * 256 + kk * 32 + quad * 8];
            short8 bv = *(short8*)&KVl[(w * 16 + l15) * 264 + kk * 32 + quad * 8];
            accX = __builtin_amdgcn_mfma_f32_16x16x32_bf16(ap, bv, accX, 0, 0, 0);
        }
    }
    #pragma unroll
    for (int r = 0; r < 4; r++)
        X[rowbase + (size_t)(q0 + quad * 4 + r) * 1024 + h * 64 + w * 16 + l15] =
            f2bf(accX[r]);
}

// ---------------------------------------------------------------------------
extern "C" void kernel_launch(void* const* d_in, const int* in_sizes, int n_in,
                              void* d_out, int out_size, void* d_ws, size_t ws_size,
                              hipStream_t stream)
{
    const float* q_in = (const float*)d_in[0];
    const float* k_in = (const float*)d_in[1];
    const float* v_in = (const float*)d_in[2];
    const int*   mask = (const int*)d_in[3];
    const float* Wq = (const float*)d_in[4];
    const float* bq = (const float*)d_in[5];
    const float* Wk = (const float*)d_in[6];
    const float* bk = (const float*)d_in[7];
    const float* Wv = (const float*)d_in[8];
    const float* bv = (const float*)d_in[9];
    const float* Wo = (const float*)d_in[10];
    const float* bo = (const float*)d_in[11];

    short* ws = (short*)d_ws;
    const size_t MEL = 4096ull * 1024;     // 4,194,304 elems per [B*S, D] tensor
    short* Qp  = ws;
    short* Kp  = ws + MEL;
    short* Vp  = ws + 2 * MEL;
    short* Xp  = ws + 3 * MEL;
    short* WqT = ws + 4 * MEL;
    short* WkT = WqT + 1024 * 1024;
    short* WvT = WkT + 1024 * 1024;
    short* WoT = WvT + 1024 * 1024;

    float* outp  = (float*)d_out;          // outputs [B,S,D] f32
    float* attnp = outp + MEL;             // attention [B,H,S,S] f32

    transpose4<<<dim3(1024), dim3(256), 0, stream>>>(Wq, Wk, Wv, Wo,
                                                     WqT, WkT, WvT, WoT);
    dim3 gg(32, 8);
    gemm_bt<false, false><<<gg, 256, 0, stream>>>(q_in, WqT, bq, Qp, 4096, 1024, 1024);
    gemm_bt<false, false><<<gg, 256, 0, stream>>>(k_in, WkT, bk, Kp, 4096, 1024, 1024);
    gemm_bt<false, false><<<gg, 256, 0, stream>>>(v_in, WvT, bv, Vp, 4096, 1024, 1024);
    attn_kernel<<<dim3(4096), dim3(256), 0, stream>>>(Qp, Kp, Vp, mask, attnp, Xp);
    gemm_bt<true, true><<<gg, 256, 0, stream>>>(Xp, WoT, bo, outp, 4096, 1024, 1024);
}

// Round 4
// 540.916 us; speedup vs baseline: 1.1997x; 1.1997x over previous
//
#include <hip/hip_runtime.h>

typedef short short8  __attribute__((ext_vector_type(8)));
typedef short short4v __attribute__((ext_vector_type(4)));
typedef float float4v __attribute__((ext_vector_type(4)));
typedef int   int4v   __attribute__((ext_vector_type(4)));

__device__ __forceinline__ short f2bf(float f) {
    unsigned u = __builtin_bit_cast(unsigned, f);
    u += 0x7fff + ((u >> 16) & 1);   // RNE
    return (short)(u >> 16);
}

// ---------------------------------------------------------------------------
// Transpose 4 weight matrices [1024,1024] f32 -> bf16: Wt[n][k] = bf16(W[k][n])
// ---------------------------------------------------------------------------
__global__ __launch_bounds__(256) void transpose4(
    const float* __restrict__ W0, const float* __restrict__ W1,
    const float* __restrict__ W2, const float* __restrict__ W3,
    short* __restrict__ T0, short* __restrict__ T1,
    short* __restrict__ T2, short* __restrict__ T3)
{
    __shared__ short Tl[64 * 72];
    const int tid = threadIdx.x;
    const int mat = blockIdx.x >> 8;
    const int t   = blockIdx.x & 255;
    const int k0 = (t >> 4) * 64, n0 = (t & 15) * 64;
    const float* W = mat == 0 ? W0 : mat == 1 ? W1 : mat == 2 ? W2 : W3;
    short*       T = mat == 0 ? T0 : mat == 1 ? T1 : mat == 2 ? T2 : T3;
    #pragma unroll
    for (int i = 0; i < 4; i++) {
        int c = tid + i * 256;
        int row = c >> 4, c4 = (c & 15) * 4;
        float4v v = *(const float4v*)&W[(size_t)(k0 + row) * 1024 + n0 + c4];
        short4v s = {f2bf(v[0]), f2bf(v[1]), f2bf(v[2]), f2bf(v[3])};
        *(short4v*)&Tl[row * 72 + c4] = s;
    }
    __syncthreads();
    #pragma unroll
    for (int i = 0; i < 2; i++) {
        int c = tid + i * 256;
        int nrow = c >> 3, k8 = (c & 7) * 8;
        short8 v;
        #pragma unroll
        for (int e = 0; e < 8; e++) v[e] = Tl[(k8 + e) * 72 + nrow];
        *(short8*)&T[(size_t)(n0 + nrow) * 1024 + k0 + k8] = v;
    }
}

// ---------------------------------------------------------------------------
// C = bf16(A) @ Bt^T + bias. 64x64 tile, BK=64, 256 threads (4 waves 2x2,
// each wave 32x32). CMODE: 0 = bf16 natural, 1 = f32 natural,
// 2 = bf16 transposed-per-batch Vt[b][n][s] (batch = row/1024).
// ---------------------------------------------------------------------------
template<int CMODE, bool A_BF16>
__global__ __launch_bounds__(256) void gemm_bt64(
    const void* __restrict__ Av, const short* __restrict__ Bt,
    const float* __restrict__ bias, void* __restrict__ Cv,
    int M, int N, int K)
{
    __shared__ short As[64 * 72];
    __shared__ short Bs[64 * 72];
    const int tid = threadIdx.x;
    const int m0 = blockIdx.x * 64, n0 = blockIdx.y * 64;
    const int w = tid >> 6, lid = tid & 63, quad = lid >> 4, l15 = lid & 15;
    const int wrow = (w >> 1) * 32, wcol = (w & 1) * 32;

    float4v acc[2][2];
    #pragma unroll
    for (int i = 0; i < 2; i++)
        #pragma unroll
        for (int j = 0; j < 2; j++) acc[i][j] = (float4v){0.f, 0.f, 0.f, 0.f};

    for (int kb = 0; kb < K; kb += 64) {
        if constexpr (A_BF16) {
            const short* A = (const short*)Av;
            #pragma unroll
            for (int i = 0; i < 2; i++) {
                int c = tid + i * 256;
                int row = c >> 3, k8 = (c & 7) * 8;
                *(short8*)&As[row * 72 + k8] =
                    *(const short8*)&A[(size_t)(m0 + row) * K + kb + k8];
            }
        } else {
            const float* A = (const float*)Av;
            #pragma unroll
            for (int i = 0; i < 4; i++) {
                int c = tid + i * 256;
                int row = c >> 4, c4 = (c & 15) * 4;
                float4v v = *(const float4v*)&A[(size_t)(m0 + row) * K + kb + c4];
                short4v s = {f2bf(v[0]), f2bf(v[1]), f2bf(v[2]), f2bf(v[3])};
                *(short4v*)&As[row * 72 + c4] = s;
            }
        }
        #pragma unroll
        for (int i = 0; i < 2; i++) {
            int c = tid + i * 256;
            int row = c >> 3, k8 = (c & 7) * 8;
            *(short8*)&Bs[row * 72 + k8] =
                *(const short8*)&Bt[(size_t)(n0 + row) * K + kb + k8];
        }
        __syncthreads();
        short8 ar0[2], ar1[2], br0[2], br1[2];
        #pragma unroll
        for (int i = 0; i < 2; i++) {
            ar0[i] = *(short8*)&As[(wrow + i * 16 + l15) * 72 + quad * 8];
            ar1[i] = *(short8*)&As[(wrow + i * 16 + l15) * 72 + 32 + quad * 8];
        }
        #pragma unroll
        for (int j = 0; j < 2; j++) {
            br0[j] = *(short8*)&Bs[(wcol + j * 16 + l15) * 72 + quad * 8];
            br1[j] = *(short8*)&Bs[(wcol + j * 16 + l15) * 72 + 32 + quad * 8];
        }
        #pragma unroll
        for (int i = 0; i < 2; i++)
            #pragma unroll
            for (int j = 0; j < 2; j++) {
                acc[i][j] = __builtin_amdgcn_mfma_f32_16x16x32_bf16(
                    ar0[i], br0[j], acc[i][j], 0, 0, 0);
                acc[i][j] = __builtin_amdgcn_mfma_f32_16x16x32_bf16(
                    ar1[i], br1[j], acc[i][j], 0, 0, 0);
            }
        __syncthreads();
    }

    #pragma unroll
    for (int j = 0; j < 2; j++) {
        int n = n0 + wcol + j * 16 + l15;
        float bj = bias[n];
        #pragma unroll
        for (int i = 0; i < 2; i++) {
            if constexpr (CMODE == 2) {
                short* Vt = (short*)Cv;
                int b = m0 >> 10;
                int sbase = (m0 & 1023) + wrow + i * 16 + quad * 4;
                short4v sv;
                #pragma unroll
                for (int r = 0; r < 4; r++) sv[r] = f2bf(acc[i][j][r] + bj);
                *(short4v*)&Vt[(size_t)b * 1048576 + (size_t)n * 1024 + sbase] = sv;
            } else {
                #pragma unroll
                for (int r = 0; r < 4; r++) {
                    int m = m0 + wrow + i * 16 + quad * 4 + r;
                    if constexpr (CMODE == 1)
                        ((float*)Cv)[(size_t)m * N + n] = acc[i][j][r] + bj;
                    else
                        ((short*)Cv)[(size_t)m * N + n] = f2bf(acc[i][j][r] + bj);
                }
            }
        }
    }
}

// ---------------------------------------------------------------------------
// Fused attention. Block = one (b,h) x 16 query rows; 4 waves split the
// 1024 key cols. K/V staged in 128-wide tiles (27.4 KB LDS total).
// S = Q Kh^T/8, mask, softmax (f32) -> P f32 to attnOut + bf16 to LDS,
// X = P @ Vh (Vt pre-transposed by the V GEMM).
// ---------------------------------------------------------------------------
__global__ __launch_bounds__(256) void attn_kernel(
    const short* __restrict__ Qp, const short* __restrict__ Kp,
    const short* __restrict__ Vt, const int* __restrict__ mask,
    float* __restrict__ attnOut, short* __restrict__ X)
{
    __shared__ short KVl[128 * 72];     // K tile [128][72] / Vt tile [64][136]
    __shared__ short Pl[16 * 136];      // per-kt bf16 P tile
    __shared__ int   maskl[1024];
    __shared__ float redmx[4][16];
    __shared__ float redsm[4][16];

    const int tid = threadIdx.x;
    const int w = tid >> 6, lid = tid & 63, quad = lid >> 4, l15 = lid & 15;
    const int bid = blockIdx.x;
    const int qb = bid & 63;
    const int bh = bid >> 6;
    const int b = bh >> 4, h = bh & 15;
    const int q0 = qb * 16;
    const size_t rowbase = (size_t)b * 1048576;

    *(int4v*)&maskl[tid * 4] = *(const int4v*)&mask[b * 1024 + tid * 4];

    // Q fragments direct from global (one-time, 16B/lane)
    short8 aq0 = *(const short8*)
        &Qp[rowbase + (size_t)(q0 + l15) * 1024 + h * 64 + quad * 8];
    short8 aq1 = *(const short8*)
        &Qp[rowbase + (size_t)(q0 + l15) * 1024 + h * 64 + 32 + quad * 8];

    // ---- S = Q K^T : accS[a] holds cols (a>>1)*128 + w*32 + (a&1)*16 + l15
    float4v accS[16];
    #pragma unroll
    for (int a = 0; a < 16; a++) accS[a] = (float4v){0.f, 0.f, 0.f, 0.f};

    for (int nk = 0; nk < 8; nk++) {
        #pragma unroll
        for (int i = 0; i < 4; i++) {
            int c = tid + i * 256;
            int row = c >> 3, k8 = (c & 7) * 8;
            *(short8*)&KVl[row * 72 + k8] = *(const short8*)
                &Kp[rowbase + (size_t)(nk * 128 + row) * 1024 + h * 64 + k8];
        }
        __syncthreads();
        #pragma unroll
        for (int jj = 0; jj < 2; jj++) {
            int nloc = w * 32 + jj * 16 + l15;
            short8 b0 = *(short8*)&KVl[nloc * 72 + quad * 8];
            short8 b1 = *(short8*)&KVl[nloc * 72 + 32 + quad * 8];
            int a = nk * 2 + jj;
            accS[a] = __builtin_amdgcn_mfma_f32_16x16x32_bf16(aq0, b0, accS[a], 0, 0, 0);
            accS[a] = __builtin_amdgcn_mfma_f32_16x16x32_bf16(aq1, b1, accS[a], 0, 0, 0);
        }
        __syncthreads();
    }

    // ---- scale + mask + softmax (f32) ----
    float mx[4] = {-3e38f, -3e38f, -3e38f, -3e38f};
    #pragma unroll
    for (int a = 0; a < 16; a++) {
        int col = (a >> 1) * 128 + w * 32 + (a & 1) * 16 + l15;
        bool keep = maskl[col] != 0;
        #pragma unroll
        for (int r = 0; r < 4; r++) {
            float s = accS[a][r] * 0.125f;
            s = keep ? s : -1e10f;
            accS[a][r] = s;
            mx[r] = fmaxf(mx[r], s);
        }
    }
    #pragma unroll
    for (int off = 1; off < 16; off <<= 1)
        #pragma unroll
        for (int r = 0; r < 4; r++) mx[r] = fmaxf(mx[r], __shfl_xor(mx[r], off));
    if (l15 == 0) {
        #pragma unroll
        for (int r = 0; r < 4; r++) redmx[w][quad * 4 + r] = mx[r];
    }
    __syncthreads();
    float mrow[4], sm[4] = {0.f, 0.f, 0.f, 0.f};
    #pragma unroll
    for (int r = 0; r < 4; r++) {
        int qr = quad * 4 + r;
        mrow[r] = fmaxf(fmaxf(redmx[0][qr], redmx[1][qr]),
                        fmaxf(redmx[2][qr], redmx[3][qr]));
    }
    #pragma unroll
    for (int a = 0; a < 16; a++)
        #pragma unroll
        for (int r = 0; r < 4; r++) {
            float e = __expf(accS[a][r] - mrow[r]);
            accS[a][r] = e;
            sm[r] += e;
        }
    #pragma unroll
    for (int off = 1; off < 16; off <<= 1)
        #pragma unroll
        for (int r = 0; r < 4; r++) sm[r] += __shfl_xor(sm[r], off);
    if (l15 == 0) {
        #pragma unroll
        for (int r = 0; r < 4; r++) redsm[w][quad * 4 + r] = sm[r];
    }
    __syncthreads();
    float inv[4];
    #pragma unroll
    for (int r = 0; r < 4; r++) {
        int qr = quad * 4 + r;
        inv[r] = 1.0f / (redsm[0][qr] + redsm[1][qr] + redsm[2][qr] + redsm[3][qr]);
    }

    // ---- per-kt: write P (f32 out + bf16 LDS) and accumulate X = P @ V ----
    const size_t abase = ((size_t)bh * 1024 + q0) * 1024;
    float4v accX = (float4v){0.f, 0.f, 0.f, 0.f};
    for (int kt = 0; kt < 8; kt++) {
        // stage Vt tile [64 d][128 s]
        #pragma unroll
        for (int i = 0; i < 4; i++) {
            int c = tid + i * 256;
            int row = c >> 4, s8 = (c & 15) * 8;
            *(short8*)&KVl[row * 136 + s8] = *(const short8*)
                &Vt[rowbase + (size_t)(h * 64 + row) * 1024 + kt * 128 + s8];
        }
        // P for this kt from registers
        #pragma unroll
        for (int jj = 0; jj < 2; jj++) {
            int a = kt * 2 + jj;
            int cl = w * 32 + jj * 16 + l15;
            int col = kt * 128 + cl;
            #pragma unroll
            for (int r = 0; r < 4; r++) {
                float p = accS[a][r] * inv[r];
                attnOut[abase + (size_t)(quad * 4 + r) * 1024 + col] = p;
                Pl[(quad * 4 + r) * 136 + cl] = f2bf(p);
            }
        }
        __syncthreads();
        #pragma unroll
        for (int kk = 0; kk < 4; kk++) {
            short8 ap = *(short8*)&Pl[l15 * 136 + kk * 32 + quad * 8];
            short8 bv = *(short8*)&KVl[(w * 16 + l15) * 136 + kk * 32 + quad * 8];
            accX = __builtin_amdgcn_mfma_f32_16x16x32_bf16(ap, bv, accX, 0, 0, 0);
        }
        __syncthreads();
    }
    #pragma unroll
    for (int r = 0; r < 4; r++)
        X[rowbase + (size_t)(q0 + quad * 4 + r) * 1024 + h * 64 + w * 16 + l15] =
            f2bf(accX[r]);
}

// ---------------------------------------------------------------------------
extern "C" void kernel_launch(void* const* d_in, const int* in_sizes, int n_in,
                              void* d_out, int out_size, void* d_ws, size_t ws_size,
                              hipStream_t stream)
{
    const float* q_in = (const float*)d_in[0];
    const float* k_in = (const float*)d_in[1];
    const float* v_in = (const float*)d_in[2];
    const int*   mask = (const int*)d_in[3];
    const float* Wq = (const float*)d_in[4];
    const float* bq = (const float*)d_in[5];
    const float* Wk = (const float*)d_in[6];
    const float* bk = (const float*)d_in[7];
    const float* Wv = (const float*)d_in[8];
    const float* bv = (const float*)d_in[9];
    const float* Wo = (const float*)d_in[10];
    const float* bo = (const float*)d_in[11];

    short* ws = (short*)d_ws;
    const size_t MEL = 4096ull * 1024;
    short* Qp  = ws;
    short* Kp  = ws + MEL;
    short* Vt  = ws + 2 * MEL;             // transposed-per-batch V [4][1024][1024]
    short* Xp  = ws + 3 * MEL;
    short* WqT = ws + 4 * MEL;
    short* WkT = WqT + 1024 * 1024;
    short* WvT = WkT + 1024 * 1024;
    short* WoT = WvT + 1024 * 1024;

    float* outp  = (float*)d_out;          // outputs [B,S,D] f32
    float* attnp = outp + MEL;             // attention [B,H,S,S] f32

    transpose4<<<dim3(1024), dim3(256), 0, stream>>>(Wq, Wk, Wv, Wo,
                                                     WqT, WkT, WvT, WoT);
    dim3 gg(64, 16);
    gemm_bt64<0, false><<<gg, 256, 0, stream>>>(q_in, WqT, bq, Qp, 4096, 1024, 1024);
    gemm_bt64<0, false><<<gg, 256, 0, stream>>>(k_in, WkT, bk, Kp, 4096, 1024, 1024);
    gemm_bt64<2, false><<<gg, 256, 0, stream>>>(v_in, WvT, bv, Vt, 4096, 1024, 1024);
    attn_kernel<<<dim3(4096), dim3(256), 0, stream>>>(Qp, Kp, Vt, mask, attnp, Xp);
    gemm_bt64<1, true><<<gg, 256, 0, stream>>>(Xp, WoT, bo, outp, 4096, 1024, 1024);
}